// Round 11
// baseline (43.680 us; speedup 1.0000x reference)
//
#include <hip/hip_runtime.h>
#include <hip/hip_bf16.h>

typedef __bf16 bf16x8 __attribute__((ext_vector_type(8)));
typedef float f32x4 __attribute__((ext_vector_type(4)));

#define G 8
#define B 32
#define D 32
#define O 32
#define K 4096   // N*T (floats per W row)
#define T 64
#define KSPLIT 2
#define KCHUNK (K / KSPLIT)   // 2048 floats
#define BK 256                // floats staged per row per step (1KB/row)
#define NSTEP (KCHUNK / BK)   // 8
#define MROWS 16              // o-rows per block

// ws: XB bf16 [K/32][B][32] = 256 KB only.
#define XB_ELEMS (B * K)

// Fused prep: threads [0,16384) build XB (MFMA B-frag order, no mask);
// threads [16384, 49152) init out[b][d][o] = bias[d][o] (gemm atomically adds).
__global__ __launch_bounds__(256) void prep_and_init(const float* __restrict__ x,
                                                     const float* __restrict__ bias,
                                                     __bf16* __restrict__ xb,
                                                     float* __restrict__ out) {
    int tid = blockIdx.x * 256 + threadIdx.x;
    if (tid < 16384) {
        int b = (tid >> 2) & 31;
        int k = (tid >> 7) * 32 + (tid & 3) * 8;
        const float4 x0 = *(const float4*)(x + b * K + k);
        const float4 x1 = *(const float4*)(x + b * K + k + 4);
        bf16x8 r;
        r[0] = (__bf16)x0.x; r[1] = (__bf16)x0.y; r[2] = (__bf16)x0.z; r[3] = (__bf16)x0.w;
        r[4] = (__bf16)x1.x; r[5] = (__bf16)x1.y; r[6] = (__bf16)x1.z; r[7] = (__bf16)x1.w;
        *(bf16x8*)(xb + (size_t)tid * 8) = r;   // flat idx == tid*8: coalesced
    } else {
        int t2 = tid - 16384;           // 32768 = B*D*O, out flat = b*1024 + d*32 + o
        out[t2] = bias[t2 & 1023];
    }
}

// Block (d, g, oh, ks): M = 16 contiguous o-rows, N = 32 b, K-half ks.
// 256 threads = 4 waves: wave wid -> (bh = wid&1, kh = wid>>1); each wave
// computes the full 16-o x 16-b quadrant bh over k-half kh; kh partials are
// reduced in-block via LDS before the atomic epilogue.
//
// Staging is REGISTER-staged (T14 split), high-occupancy (16 waves/CU):
//   per step each wave issues 4x 1KB-contiguous global_load_dwordx4
//   (row = wid*4+j, lane*16B) + 4 xb loads, all BEFORE the barrier; the
//   ds_write of the PREVIOUS step's regs waits only on those older loads
//   (in-order vmcnt), so the new loads stay in flight through compute.
// LDS write applies the XOR chunk-swizzle (row&7)<<4 directly (reg-staged,
// so no global_load_lds linear-dest restriction); reads use the same XOR.
__global__ __launch_bounds__(256, 4) void gemm_main(const float* __restrict__ W,
                                                    const __bf16* __restrict__ xb,
                                                    const float* __restrict__ mask,
                                                    const float* __restrict__ y,
                                                    float* __restrict__ out) {
    __shared__ float ldsW[MROWS * BK];   // 16 KB single buffer
    const int d = blockIdx.x, g = blockIdx.y;
    const int oh = blockIdx.z & 1, ks = blockIdx.z >> 1;
    const int wid  = threadIdx.x >> 6;
    const int lane = threadIdx.x & 63;
    const int bh = wid & 1, kh = wid >> 1;
    const int l15 = lane & 15, g16 = lane >> 4;

    // A-fragment read base: row = l15, byte x = ktl*128 + g16*32 (^16 hi), swizzled
    const int lds_ro = l15 * 1024 + ((g16 * 32) ^ ((l15 & 7) * 16));

    // mask row o = oh*16 + l15; lane needs t = (ktl&1)*32 + g16*8 + j
    const float* mrow = mask + (oh * 16 + l15) * T + g16 * 8;
    const float4 me0 = *(const float4*)(mrow);
    const float4 me1 = *(const float4*)(mrow + 4);
    const float4 mo0 = *(const float4*)(mrow + 32);
    const float4 mo1 = *(const float4*)(mrow + 36);

    // XB: k-tile kt = ks*64 + step*8 + ktl; elem = kt*1024 + b*32 + g16*8
    const __bf16* xbl = xb + (size_t)(ks * (KCHUNK / 32)) * 1024
                           + (bh * 16 + l15) * 32 + g16 * 8;

    // W rows for this block: o = oh*16 + 0..15, contiguous; wave stages rows wid*4..+3
    const size_t wrow0 = ((size_t)(g * D + d) * O + oh * 16) * K + (size_t)ks * KCHUNK;

    f32x4 acc = {0.f, 0.f, 0.f, 0.f};

#define REGLOAD(wreg, step)                                                       \
    {                                                                             \
        _Pragma("unroll")                                                         \
        for (int j = 0; j < 4; ++j)                                               \
            wreg[j] = *(const f32x4*)(W + wrow0 + (size_t)(wid * 4 + j) * K       \
                                      + (step) * BK + lane * 4);                  \
    }
#define XLOAD(xreg, step)                                                         \
    {                                                                             \
        _Pragma("unroll")                                                         \
        for (int s2 = 0; s2 < 4; ++s2)                                            \
            xreg[s2] = *(const bf16x8*)(xbl + ((size_t)(step) * 8 + kh * 4 + s2)  \
                                              * 1024);                            \
    }
#define DSWRITE(wreg)                                                             \
    {                                                                             \
        _Pragma("unroll")                                                         \
        for (int j = 0; j < 4; ++j) {                                             \
            const int row = wid * 4 + j;                                          \
            *(f32x4*)((char*)ldsW + row * 1024                                    \
                      + ((lane * 16) ^ ((row & 7) * 16))) = wreg[j];              \
        }                                                                         \
    }
#define COMPUTE(xreg)                                                             \
    {                                                                             \
        _Pragma("unroll")                                                         \
        for (int s2 = 0; s2 < 4; ++s2) {                                          \
            const int ktl = kh * 4 + s2;                                          \
            const int a0 = lds_ro + ktl * 128;                                    \
            const f32x4 alo = *(const f32x4*)((char*)ldsW + a0);                  \
            const f32x4 ahi = *(const f32x4*)((char*)ldsW + (a0 ^ 16));           \
            const float4 ms0 = (ktl & 1) ? mo0 : me0;                             \
            const float4 ms1 = (ktl & 1) ? mo1 : me1;                             \
            bf16x8 af;                                                            \
            af[0] = (__bf16)(alo[0] * ms0.x); af[1] = (__bf16)(alo[1] * ms0.y);   \
            af[2] = (__bf16)(alo[2] * ms0.z); af[3] = (__bf16)(alo[3] * ms0.w);   \
            af[4] = (__bf16)(ahi[0] * ms1.x); af[5] = (__bf16)(ahi[1] * ms1.y);   \
            af[6] = (__bf16)(ahi[2] * ms1.z); af[7] = (__bf16)(ahi[3] * ms1.w);   \
            acc = __builtin_amdgcn_mfma_f32_16x16x32_bf16(af, xreg[s2], acc,      \
                                                          0, 0, 0);               \
        }                                                                         \
    }

    f32x4 wrA[4], wrB[4];
    bf16x8 xA[4], xB[4];

    REGLOAD(wrA, 0);
    XLOAD(xA, 0);

    for (int sp = 0; sp < NSTEP; sp += 2) {
        // even step: consume A, prefetch B (stays in flight through compute)
        DSWRITE(wrA);                    // waits only wrA (oldest, in-order vmcnt)
        REGLOAD(wrB, sp + 1);
        XLOAD(xB, sp + 1);
        __syncthreads();
        COMPUTE(xA);
        __syncthreads();

        // odd step: consume B, prefetch A
        DSWRITE(wrB);
        if (sp + 2 < NSTEP) {
            REGLOAD(wrA, sp + 2);
            XLOAD(xA, sp + 2);
        }
        __syncthreads();
        COMPUTE(xB);
        __syncthreads();
    }
#undef REGLOAD
#undef XLOAD
#undef DSWRITE
#undef COMPUTE

    // In-block kh-reduction (LDS reuse, already past the last compute barrier)
    if (kh == 1)
        *(f32x4*)((char*)ldsW + (bh * 64 + lane) * 16) = acc;
    __syncthreads();
    if (kh == 0) {
        const f32x4 other = *(const f32x4*)((char*)ldsW + (bh * 64 + lane) * 16);
        acc += other;
        // C/D: lane holds D[row=g16*4+i][col=l15]; row = o-local, col = b-local
        const int bg = bh * 16 + l15;
        const float yv = y[bg * G + g];
        float* op = out + bg * (D * O) + d * O + oh * 16 + g16 * 4;
        #pragma unroll
        for (int i = 0; i < 4; ++i)
            unsafeAtomicAdd(op + i, yv * acc[i]);
    }
}

extern "C" void kernel_launch(void* const* d_in, const int* in_sizes, int n_in,
                              void* d_out, int out_size, void* d_ws, size_t ws_size,
                              hipStream_t stream) {
    const float* x    = (const float*)d_in[0];
    const float* y    = (const float*)d_in[1];
    const float* w    = (const float*)d_in[2];
    const float* bias = (const float*)d_in[3];
    const float* mask = (const float*)d_in[4];
    float* out = (float*)d_out;

    __bf16* xbp = (__bf16*)d_ws;

    prep_and_init<<<192, 256, 0, stream>>>(x, bias, xbp, out);
    gemm_main<<<dim3(D, G, 4), 256, 0, stream>>>(w, xbp, mask, y, out);
}

// Round 12
// 37.597 us; speedup vs baseline: 1.1618x; 1.1618x over previous
//
#include <hip/hip_runtime.h>
#include <hip/hip_bf16.h>

typedef __bf16 bf16x8 __attribute__((ext_vector_type(8)));
typedef float f32x4 __attribute__((ext_vector_type(4)));

#define G 8
#define B 32
#define D 32
#define O 32
#define K 4096   // N*T (floats per W row)
#define T 64
#define KSPLIT 2
#define KCHUNK (K / KSPLIT)   // 2048 floats
#define BK 256                // floats staged per row per step (1KB burst)
#define NSTEP (KCHUNK / BK)   // 8
#define MROWS 16              // o-rows per block

// ws: XB bf16 [K/32][B][32] = 256 KB only.
#define XB_ELEMS (B * K)

// Fused prep: threads [0,16384) build XB (MFMA B-frag order, no mask);
// threads [16384, 49152) init out[b][d][o] = bias[d][o] (gemm atomically adds).
__global__ __launch_bounds__(256) void prep_and_init(const float* __restrict__ x,
                                                     const float* __restrict__ bias,
                                                     __bf16* __restrict__ xb,
                                                     float* __restrict__ out) {
    int tid = blockIdx.x * 256 + threadIdx.x;
    if (tid < 16384) {
        int b = (tid >> 2) & 31;
        int k = (tid >> 7) * 32 + (tid & 3) * 8;
        const float4 x0 = *(const float4*)(x + b * K + k);
        const float4 x1 = *(const float4*)(x + b * K + k + 4);
        bf16x8 r;
        r[0] = (__bf16)x0.x; r[1] = (__bf16)x0.y; r[2] = (__bf16)x0.z; r[3] = (__bf16)x0.w;
        r[4] = (__bf16)x1.x; r[5] = (__bf16)x1.y; r[6] = (__bf16)x1.z; r[7] = (__bf16)x1.w;
        *(bf16x8*)(xb + (size_t)tid * 8) = r;   // flat idx == tid*8: coalesced
    } else {
        int t2 = tid - 16384;           // 32768 = B*D*O, out flat = b*1024 + d*32 + o
        out[t2] = bias[t2 & 1023];
    }
}

// Block (d, g, oh, ks): M = 16 contiguous o-rows, N = 32 b, K-half ks.
// 128 threads = 2 waves; wave bh covers b in [16*bh, 16*bh+16).
// W staged via global_load_lds, 1KB contiguous burst per o-row per step;
// aux=2 (NT/SLC): W is consumed exactly once per line by a single
// instruction -- bypass L2 allocation so the streaming 16MB/XCD doesn't
// thrash the 4MB L2 (keeps XB resident; avoids alloc/evict rate limit).
// XOR chunk-swizzle (row&7)<<4 on source AND lds-read addrs (rule 21).
// mask[o][t] applied to the A-fragment before bf16 convert.
// 32KB LDS/block -> 4 independent blocks/CU.
// Epilogue: out[b][d][o] += y[b][g] * acc  (unsafeAtomicAdd, 16 adders/elem).
__global__ __launch_bounds__(128) void gemm_main(const float* __restrict__ W,
                                                 const __bf16* __restrict__ xb,
                                                 const float* __restrict__ mask,
                                                 const float* __restrict__ y,
                                                 float* __restrict__ out) {
    __shared__ float ldsW[2][MROWS * BK];   // 2 x 16 KB
    const int d = blockIdx.x, g = blockIdx.y;
    const int oh = blockIdx.z & 1, ks = blockIdx.z >> 1;
    const int wid  = threadIdx.x >> 6;      // 0..1 = bh
    const int lane = threadIdx.x & 63;
    const int bh = wid;
    const int l15 = lane & 15, g16 = lane >> 4;

    // A-fragment: local row = l15, within-row byte = s*128 + g16*32 (+16 hi), swizzled
    const int lds_ro = l15 * 1024 + ((g16 * 32) ^ ((l15 & 7) * 16));

    // mask row o = oh*16 + l15; lane needs t = (s&1)*32 + g16*8 + j
    const float* mrow = mask + (oh * 16 + l15) * T + g16 * 8;
    const float4 me0 = *(const float4*)(mrow);
    const float4 me1 = *(const float4*)(mrow + 4);
    const float4 mo0 = *(const float4*)(mrow + 32);
    const float4 mo1 = *(const float4*)(mrow + 36);

    // XB: k-tile kt = ks*64 + step*8 + s; elem = kt*1024 + b*32 + g16*8
    const __bf16* xbl = xb + (size_t)(ks * (KCHUNK / 32)) * 1024
                           + (bh * 16 + l15) * 32 + g16 * 8;

    // staging: wave wid stages local rows 8*wid .. 8*wid+7
    const size_t wrow0 = ((size_t)(g * D + d) * O + oh * 16 + 8 * wid) * K
                         + (size_t)ks * KCHUNK;

    f32x4 acc = {0.f, 0.f, 0.f, 0.f};

#define STAGE(buf, step)                                                          \
    {                                                                             \
        _Pragma("unroll")                                                         \
        for (int i = 0; i < 8; ++i) {                                             \
            const int row = 8 * wid + i;                                          \
            const char* src = (const char*)(W + wrow0 + (size_t)i * K             \
                                            + (size_t)(step) * BK)                \
                              + ((lane * 16) ^ (i * 16));                         \
            __builtin_amdgcn_global_load_lds(                                     \
                (const __attribute__((address_space(1))) void*)src,               \
                (__attribute__((address_space(3))) void*)((char*)&ldsW[buf][0]    \
                                                          + row * 1024),          \
                16, 0, /*aux=NT*/ 2);                                             \
        }                                                                         \
    }

    STAGE(0, 0);
    __syncthreads();

    int cur = 0;
    for (int step = 0; step < NSTEP; ++step) {
        if (step + 1 < NSTEP) STAGE(cur ^ 1, step + 1);

        const char* lb = (const char*)&ldsW[cur][0];
        const __bf16* xs = xbl + (size_t)(step * 8) * 1024;
        #pragma unroll
        for (int s = 0; s < 8; ++s) {
            const int a0 = lds_ro + s * 128;
            const f32x4 alo = *(const f32x4*)(lb + a0);
            const f32x4 ahi = *(const f32x4*)(lb + (a0 ^ 16));
            const float4 ms0 = (s & 1) ? mo0 : me0;
            const float4 ms1 = (s & 1) ? mo1 : me1;
            bf16x8 af;
            af[0] = (__bf16)(alo[0] * ms0.x); af[1] = (__bf16)(alo[1] * ms0.y);
            af[2] = (__bf16)(alo[2] * ms0.z); af[3] = (__bf16)(alo[3] * ms0.w);
            af[4] = (__bf16)(ahi[0] * ms1.x); af[5] = (__bf16)(ahi[1] * ms1.y);
            af[6] = (__bf16)(ahi[2] * ms1.z); af[7] = (__bf16)(ahi[3] * ms1.w);
            const bf16x8 bfr = *(const bf16x8*)(xs + (size_t)s * 1024);
            acc = __builtin_amdgcn_mfma_f32_16x16x32_bf16(af, bfr, acc, 0, 0, 0);
        }
        __syncthreads();
        cur ^= 1;
    }
#undef STAGE

    // C/D: lane holds D[row=g16*4+i][col=l15]; row = o-in-tile, col = b-in-tile
    const int bg = bh * 16 + l15;                 // global b
    const float yv = y[bg * G + g];
    float* op = out + bg * (D * O) + d * O + oh * 16;
    #pragma unroll
    for (int i = 0; i < 4; ++i)
        unsafeAtomicAdd(op + g16 * 4 + i, yv * acc[i]);
}

extern "C" void kernel_launch(void* const* d_in, const int* in_sizes, int n_in,
                              void* d_out, int out_size, void* d_ws, size_t ws_size,
                              hipStream_t stream) {
    const float* x    = (const float*)d_in[0];
    const float* y    = (const float*)d_in[1];
    const float* w    = (const float*)d_in[2];
    const float* bias = (const float*)d_in[3];
    const float* mask = (const float*)d_in[4];
    float* out = (float*)d_out;

    __bf16* xbp = (__bf16*)d_ws;

    prep_and_init<<<192, 256, 0, stream>>>(x, bias, xbp, out);
    gemm_main<<<dim3(D, G, 4), 128, 0, stream>>>(w, xbp, mask, y, out);
}